// Round 8
// baseline (5219.864 us; speedup 1.0000x reference)
//
#include <hip/hip_runtime.h>

// GRU encoder: B=128, K=512, I=512, H=512.
// R14: depth-2 domain interleave. Each rec wave owns TWO independent batch
// domains (bg=2h, 2h+1) and alternates phases A,B,A,B...: domain X's
// publish->LLC->consume latency hides under domain Y's full compute phase.
// No readiness spin: bulk tagged loads issue optimistically (slack = 1 phase),
// per-tile validate + individual retry (R13 machinery). vmcnt scheme is
// entry-invariant (in-order completion; WCNT(8,8,8,0) with 8-load groups), so
// leftover xg-prefetch/store-acks drain transparently.
// GEMM: R8 fused role-split (overlap measured ~free): grid 512, blocks 32..511
// compute x-gates for chunk c+1 (CH=32, xg double-buffer). W_hh in 96KB LDS.
// Workspace: [ xg0 25,165,824 | xg1 25,165,824 | hbt 524,288 ] = 50,855,936 B.

#define CH 32
#define XG_BYTES (CH * 128 * 1536 * 4)
#define HBT_BYTES (2 * 128 * 256 * 8)

typedef float  floatx4 __attribute__((ext_vector_type(4)));
typedef short  shortx8 __attribute__((ext_vector_type(8)));
typedef unsigned int uintx4 __attribute__((ext_vector_type(4)));

__device__ __forceinline__ unsigned short f2bf(float f) {
    unsigned int uu = __float_as_uint(f);
    uu = (uu + 0x7FFFu + ((uu >> 16) & 1u)) >> 16;   // RNE; finite normals only
    return (unsigned short)uu;
}

__global__ __launch_bounds__(256, 1)
void gru_fused(const float* __restrict__ vis, const float* __restrict__ Wih,
               const float* __restrict__ bih, const float* __restrict__ Whh,
               const float* __restrict__ bhh,
               const float* __restrict__ xgR, float* __restrict__ xgW,
               unsigned long long* __restrict__ hbt, float* __restrict__ out,
               int kg0, int gemm_kg0, int do_rec, int do_gemm) {
    __shared__ union {
        unsigned short Wl[96 * 512];                       // rec: swizzled W_hh slice
        struct { unsigned short Ast[64][40], Bst[64][40]; } g;  // gemm tiles
    } sh;

    const int bx = blockIdx.x, t = threadIdx.x;
    const int wave = t >> 6, lane = t & 63, quad = lane >> 4, l16 = lane & 15;

    if (do_rec && bx < 32) {
        // ================= REC ROLE: two domains per wave =================
        __builtin_amdgcn_s_setprio(2);
        const int ug = bx & 15, half = bx >> 4;
        const int u0 = ug * 32;
        const int mt = wave & 1, u16 = wave >> 1;
        const int u = u0 + u16 * 16 + l16;        // this lane's unit column

        // stage W_hh slice -> LDS (bf16, XOR-swizzled)
        for (int i = t; i < 96 * 128; i += 256) {
            const int r = i >> 7, cq = i & 127;
            const int g = r >> 5, lu = r & 31;
            const float* p = Whh + ((size_t)(g * 512 + u0 + lu)) * 512 + cq * 4;
            float4 vv = *(const float4*)p;
            ushort4 b4;
            b4.x = f2bf(vv.x); b4.y = f2bf(vv.y); b4.z = f2bf(vv.z); b4.w = f2bf(vv.w);
            *(ushort4*)&sh.Wl[r * 512 + ((cq * 4) ^ ((r & 7) << 3))] = b4;
        }
        __syncthreads();

        const float bhr = bhh[u], bhz = bhh[512 + u], bhn = bhh[1024 + u];
        const int rb = u16 * 16 + l16, xrw = (rb & 7) << 3;

        const int b0A = (half * 2) * 32,     b0B = (half * 2 + 1) * 32;
        const int rrA = b0A + mt * 16 + l16, rrB = b0B + mt * 16 + l16;
        const int bbA = b0A + mt * 16 + quad * 4, bbB = b0B + mt * 16 + quad * 4;

        float hpA[4], hpB[4];
        if (kg0 == 0) {
            #pragma unroll
            for (int reg = 0; reg < 4; ++reg) { hpA[reg] = 0.f; hpB[reg] = 0.f; }
        } else {
            #pragma unroll
            for (int reg = 0; reg < 4; ++reg) {
                hpA[reg] = out[(size_t)(bbA + reg) * 512 + u];
                hpB[reg] = out[(size_t)(bbB + reg) * 512 + u];
            }
        }

        // prologue xg for s=0, both domains
        float xrA[4], xzA[4], xnA[4], xrB[4], xzB[4], xnB[4];
        #pragma unroll
        for (int reg = 0; reg < 4; ++reg) {
            const float* pa = xgR + ((size_t)(bbA + reg)) * 1536 + u;
            xrA[reg] = pa[0]; xzA[reg] = pa[512]; xnA[reg] = pa[1024];
            const float* pb = xgR + ((size_t)(bbB + reg)) * 1536 + u;
            xrB[reg] = pb[0]; xzB[reg] = pb[512]; xnB[reg] = pb[1024];
        }

#define WCNT(N) asm volatile("s_waitcnt vmcnt(" #N ")" ::: "memory"); \
                __builtin_amdgcn_sched_barrier(0);
#define LDQA(i, OFF) asm volatile("global_load_dwordx4 %0, %1, off offset:" OFF " sc0 sc1" \
        : "=v"(Qa[i].v) : "v"(hbp) : "memory");
#define LDQB(i, OFF) asm volatile("global_load_dwordx4 %0, %1, off offset:" OFF " sc0 sc1" \
        : "=v"(Qb[i].v) : "v"(hbp) : "memory");
#define PROC(q0, q1, KT) { \
    unsigned int e = (q0.d[1] ^ expv) | (q0.d[3] ^ expv) \
                   | (q1.d[1] ^ expv) | (q1.d[3] ^ expv); \
    if (__ballot(e != 0u) == 0ull) { \
        union { unsigned int d[4]; shortx8 v; } afu; \
        afu.d[0] = q0.d[0]; afu.d[1] = q0.d[2]; \
        afu.d[2] = q1.d[0]; afu.d[3] = q1.d[2]; \
        const int co = ((KT) * 32 + quad * 8) ^ xrw; \
        shortx8 bRf = *(const shortx8*)&sh.Wl[(size_t)rb * 512 + co]; \
        shortx8 bZf = *(const shortx8*)&sh.Wl[(size_t)(32 + rb) * 512 + co]; \
        shortx8 bNf = *(const shortx8*)&sh.Wl[(size_t)(64 + rb) * 512 + co]; \
        aR = __builtin_amdgcn_mfma_f32_16x16x32_bf16(afu.v, bRf, aR, 0, 0, 0); \
        aZ = __builtin_amdgcn_mfma_f32_16x16x32_bf16(afu.v, bZf, aZ, 0, 0, 0); \
        aN = __builtin_amdgcn_mfma_f32_16x16x32_bf16(afu.v, bNf, aN, 0, 0, 0); \
        done |= (1u << (KT)); \
    } }
#define PHASE(RR, BB, HP, XR, XZ, XN)                                           \
{                                                                               \
    floatx4 aR = {0,0,0,0}, aZ = {0,0,0,0}, aN = {0,0,0,0};                     \
    if (kg > 0) {                                                               \
        const unsigned int expv = (unsigned int)(kg - 1);                       \
        const unsigned long long* hbp = hbt + (size_t)((kg - 1) & 1) * 32768    \
                                       + (size_t)(RR) * 256 + quad * 4;         \
        union QT { uintx4 v; unsigned int d[4]; } Qa[8], Qb[8];                 \
        unsigned int done = 0u;                                                 \
        LDQA(0,"0")    LDQA(1,"16")   LDQA(2,"128")  LDQA(3,"144")              \
        LDQA(4,"256")  LDQA(5,"272")  LDQA(6,"384")  LDQA(7,"400")              \
        LDQB(0,"512")  LDQB(1,"528")  LDQB(2,"640")  LDQB(3,"656")              \
        LDQB(4,"768")  LDQB(5,"784")  LDQB(6,"896")  LDQB(7,"912")              \
        WCNT(8)                                                                 \
        PROC(Qa[0], Qa[1], 0) PROC(Qa[2], Qa[3], 1)                             \
        PROC(Qa[4], Qa[5], 2) PROC(Qa[6], Qa[7], 3)                             \
        LDQA(0,"1024") LDQA(1,"1040") LDQA(2,"1152") LDQA(3,"1168")             \
        LDQA(4,"1280") LDQA(5,"1296") LDQA(6,"1408") LDQA(7,"1424")             \
        WCNT(8)                                                                 \
        PROC(Qb[0], Qb[1], 4) PROC(Qb[2], Qb[3], 5)                             \
        PROC(Qb[4], Qb[5], 6) PROC(Qb[6], Qb[7], 7)                             \
        LDQB(0,"1536") LDQB(1,"1552") LDQB(2,"1664") LDQB(3,"1680")             \
        LDQB(4,"1792") LDQB(5,"1808") LDQB(6,"1920") LDQB(7,"1936")             \
        WCNT(8)                                                                 \
        PROC(Qa[0], Qa[1], 8)  PROC(Qa[2], Qa[3], 9)                            \
        PROC(Qa[4], Qa[5], 10) PROC(Qa[6], Qa[7], 11)                           \
        WCNT(0)                                                                 \
        PROC(Qb[0], Qb[1], 12) PROC(Qb[2], Qb[3], 13)                           \
        PROC(Qb[4], Qb[5], 14) PROC(Qb[6], Qb[7], 15)                           \
        while (done != 0xFFFFu) {                                               \
            for (int kt = 0; kt < 16; ++kt) {                                   \
                if (done & (1u << kt)) continue;                                \
                const unsigned long long* tp = hbp + (size_t)kt * 16;           \
                asm volatile("global_load_dwordx4 %0, %1, off offset:0 sc0 sc1" \
                             : "=v"(Qa[0].v) : "v"(tp) : "memory");             \
                asm volatile("global_load_dwordx4 %0, %1, off offset:16 sc0 sc1"\
                             : "=v"(Qa[1].v) : "v"(tp) : "memory");             \
                WCNT(0)                                                         \
                PROC(Qa[0], Qa[1], kt)                                          \
            }                                                                   \
        }                                                                       \
    }                                                                           \
    unsigned long long* hdst = hbt + (size_t)(kg & 1) * 32768;                  \
    const unsigned long long tagv = ((unsigned long long)(unsigned int)kg) << 32; \
    _Pragma("unroll")                                                           \
    for (int reg = 0; reg < 4; ++reg) {                                         \
        const float r = 1.f / (1.f + __expf(-((XR)[reg] + aR[reg] + bhr)));     \
        const float z = 1.f / (1.f + __expf(-((XZ)[reg] + aZ[reg] + bhz)));     \
        const float nv = (XN)[reg] + r * (aN[reg] + bhn);                       \
        const float n = 1.f - 2.f / (__expf(2.f * nv) + 1.f);                   \
        const float h = (1.f - z) * n + z * (HP)[reg];                          \
        (HP)[reg] = h;                                                          \
        const float h_odd = __shfl_xor(h, 1);                                   \
        if (!(lane & 1)) {                                                      \
            unsigned long long val = tagv |                                     \
                (unsigned long long)((unsigned int)f2bf(h) |                    \
                                     ((unsigned int)f2bf(h_odd) << 16));        \
            __hip_atomic_store(hdst + (size_t)((BB) + reg) * 256 + (u >> 1),    \
                               val, __ATOMIC_RELAXED, __HIP_MEMORY_SCOPE_AGENT);\
        }                                                                       \
    }                                                                           \
    if (s + 1 < CH) {                                                           \
        _Pragma("unroll")                                                       \
        for (int reg = 0; reg < 4; ++reg) {                                     \
            const float* xgp = xgR + ((size_t)(s + 1) * 128 + (BB) + reg) * 1536 + u; \
            (XR)[reg] = xgp[0]; (XZ)[reg] = xgp[512]; (XN)[reg] = xgp[1024];    \
        }                                                                       \
    }                                                                           \
}

        for (int s = 0; s < CH; ++s) {
            const int kg = kg0 + s;
            PHASE(rrA, bbA, hpA, xrA, xzA, xnA)
            PHASE(rrB, bbB, hpB, xrB, xzB, xnB)
        }
#undef WCNT
#undef LDQA
#undef LDQB
#undef PROC
#undef PHASE

        // running h -> out (carry between dispatches; final dispatch = h[511])
        #pragma unroll
        for (int reg = 0; reg < 4; ++reg) {
            out[(size_t)(bbA + reg) * 512 + u] = hpA[reg];
            out[(size_t)(bbB + reg) * 512 + u] = hpB[reg];
        }
        return;
    }

    // ================= GEMM ROLE: x-gates for the NEXT chunk =================
    if (!do_gemm) return;
    const int NG = do_rec ? ((int)gridDim.x - 32) : (int)gridDim.x;
    const int gid = do_rec ? bx - 32 : bx;

    for (int T = gid; T < 24 * 64; T += NG) {    // 24 g-tiles x 64 m-tiles (CH=32)
        const int g0 = (T % 24) * 64;
        const int m0 = (T / 24) * 64;            // chunk-local m = kc*128 + b
        const int kc = m0 >> 7;
        const int b0 = m0 & 127;
        const int kg = gemm_kg0 + kc;

        floatx4 acc[4] = {{0,0,0,0},{0,0,0,0},{0,0,0,0},{0,0,0,0}};

        for (int ki = 0; ki < 16; ++ki) {
            const int i0 = ki * 32;
            #pragma unroll
            for (int rep = 0; rep < 2; ++rep) {
                const int r = (t >> 3) + rep * 32;
                const int c = (t & 7) * 4;
                float4 av = *(const float4*)(vis + ((size_t)(b0 + r) * 512 + kg) * 512 + i0 + c);
                ushort4 ab; ab.x = f2bf(av.x); ab.y = f2bf(av.y); ab.z = f2bf(av.z); ab.w = f2bf(av.w);
                *(ushort4*)&sh.g.Ast[r][c] = ab;
                float4 bv = *(const float4*)(Wih + (size_t)(g0 + r) * 512 + i0 + c);
                ushort4 bb; bb.x = f2bf(bv.x); bb.y = f2bf(bv.y); bb.z = f2bf(bv.z); bb.w = f2bf(bv.w);
                *(ushort4*)&sh.g.Bst[r][c] = bb;
            }
            __syncthreads();
            shortx8 afr = *(const shortx8*)(&sh.g.Ast[wave * 16 + l16][quad * 8]);
            #pragma unroll
            for (int nb = 0; nb < 4; ++nb) {
                shortx8 bfr = *(const shortx8*)(&sh.g.Bst[nb * 16 + l16][quad * 8]);
                acc[nb] = __builtin_amdgcn_mfma_f32_16x16x32_bf16(afr, bfr, acc[nb], 0, 0, 0);
            }
            __syncthreads();
        }
        #pragma unroll
        for (int nb = 0; nb < 4; ++nb) {
            const int g = g0 + nb * 16 + l16;
            const float bi = bih[g];
            #pragma unroll
            for (int reg = 0; reg < 4; ++reg) {
                const int m = m0 + wave * 16 + quad * 4 + reg;
                xgW[(size_t)m * 1536 + g] = acc[nb][reg] + bi;
            }
        }
    }
}

extern "C" void kernel_launch(void* const* d_in, const int* in_sizes, int n_in,
                              void* d_out, int out_size, void* d_ws, size_t ws_size,
                              hipStream_t stream) {
    const float* vis = (const float*)d_in[0];
    const float* Wih = (const float*)d_in[1];
    const float* Whh = (const float*)d_in[2];
    const float* bih = (const float*)d_in[3];
    const float* bhh = (const float*)d_in[4];
    float* out = (float*)d_out;

    char* ws = (char*)d_ws;
    float* xg0 = (float*)ws;
    float* xg1 = (float*)(ws + XG_BYTES);
    unsigned long long* hbt = (unsigned long long*)(ws + 2 * XG_BYTES);

    // 0xFF tags never match any step 0..511; re-armed every replay.
    hipMemsetAsync(hbt, 0xFF, HBT_BYTES, stream);

    float* bufs[2] = {xg0, xg1};

    // dispatch 0: GEMM only -> chunk 0 into xg0
    gru_fused<<<512, 256, 0, stream>>>(vis, Wih, bih, Whh, bhh,
                                       xg0, xg0, hbt, out,
                                       0, 0, 0, 1);
    // fused dispatches: rec chunk i (reads bufs[i&1]) + gemm chunk i+1
    for (int i = 0; i < 16; ++i) {
        gru_fused<<<512, 256, 0, stream>>>(vis, Wih, bih, Whh, bhh,
                                           bufs[i & 1], bufs[(i + 1) & 1],
                                           hbt, out,
                                           i * CH, (i + 1) * CH, 1, (i < 15) ? 1 : 0);
    }
}